// Round 1
// baseline (842.044 us; speedup 1.0000x reference)
//
#include <hip/hip_runtime.h>
#include <hip/hip_bf16.h>
#include <math.h>

#define IN   128
#define HID  64
#define HEADS 4
#define NCLS 10

__device__ __forceinline__ float lrelu02(float x) { return x > 0.f ? x : 0.2f * x; }

// ---------------- K1a: h0 = x @ W_pre  (n x 128)(128 x 64) ----------------
__global__ __launch_bounds__(256) void k_pre(const float* __restrict__ x,
                                             const float* __restrict__ Wp,
                                             float* __restrict__ h0, int n)
{
    __shared__ float sW[IN * HID];        // 32 KB
    __shared__ float sx[64][IN + 4];      // 33.8 KB (pad 4 -> 2-way bank alias, free)
    int t = threadIdx.x;
    for (int i = 4 * t; i < IN * HID; i += 1024)
        *(float4*)&sW[i] = *(const float4*)&Wp[i];
    int row0 = blockIdx.x * 64;
    for (int i = t; i < 64 * (IN / 4); i += 256) {
        int r = i >> 5;            // 32 float4 per row
        int c4 = (i & 31) * 4;
        int row = row0 + r;
        float4 v = make_float4(0.f, 0.f, 0.f, 0.f);
        if (row < n) v = *(const float4*)&x[(size_t)row * IN + c4];
        *(float4*)&sx[r][c4] = v;
    }
    __syncthreads();
    int tc = t & 15, tr = t >> 4;
    int c0 = tc * 4, r0 = tr * 4;
    float acc[4][4] = {};
    #pragma unroll 4
    for (int k = 0; k < IN; k++) {
        float4 w = *(float4*)&sW[k * HID + c0];
        #pragma unroll
        for (int j = 0; j < 4; j++) {
            float xv = sx[r0 + j][k];
            acc[j][0] += xv * w.x; acc[j][1] += xv * w.y;
            acc[j][2] += xv * w.z; acc[j][3] += xv * w.w;
        }
    }
    #pragma unroll
    for (int j = 0; j < 4; j++) {
        int row = row0 + r0 + j;
        if (row < n)
            *(float4*)&h0[(size_t)row * HID + c0] =
                make_float4(acc[j][0], acc[j][1], acc[j][2], acc[j][3]);
    }
}

// ---------------- K1b: xl = h0@Wl+bl, xr = h0@Wr+br ----------------
__global__ __launch_bounds__(256) void k_lr(const float* __restrict__ h0,
                                            const float* __restrict__ Wl, const float* __restrict__ bl,
                                            const float* __restrict__ Wr, const float* __restrict__ br,
                                            float* __restrict__ xl, float* __restrict__ xr, int n)
{
    __shared__ float sWl[HID * HID];   // 16 KB
    __shared__ float sWr[HID * HID];   // 16 KB
    __shared__ float sh[64][HID + 4];  // 17.4 KB
    __shared__ float sbl[HID], sbr[HID];
    int t = threadIdx.x;
    for (int i = 4 * t; i < HID * HID; i += 1024) {
        *(float4*)&sWl[i] = *(const float4*)&Wl[i];
        *(float4*)&sWr[i] = *(const float4*)&Wr[i];
    }
    if (t < HID) { sbl[t] = bl[t]; sbr[t] = br[t]; }
    int row0 = blockIdx.x * 64;
    for (int i = t; i < 64 * (HID / 4); i += 256) {
        int r = i >> 4, c4 = (i & 15) * 4;
        int row = row0 + r;
        float4 v = make_float4(0.f, 0.f, 0.f, 0.f);
        if (row < n) v = *(const float4*)&h0[(size_t)row * HID + c4];
        *(float4*)&sh[r][c4] = v;
    }
    __syncthreads();
    int tc = t & 15, tr = t >> 4;
    int c0 = tc * 4, r0 = tr * 4;
    float accl[4][4] = {}, accr[4][4] = {};
    #pragma unroll 4
    for (int k = 0; k < HID; k++) {
        float4 wl = *(float4*)&sWl[k * HID + c0];
        float4 wr = *(float4*)&sWr[k * HID + c0];
        #pragma unroll
        for (int j = 0; j < 4; j++) {
            float hv = sh[r0 + j][k];
            accl[j][0] += hv * wl.x; accl[j][1] += hv * wl.y;
            accl[j][2] += hv * wl.z; accl[j][3] += hv * wl.w;
            accr[j][0] += hv * wr.x; accr[j][1] += hv * wr.y;
            accr[j][2] += hv * wr.z; accr[j][3] += hv * wr.w;
        }
    }
    float4 b4l = *(float4*)&sbl[c0];
    float4 b4r = *(float4*)&sbr[c0];
    #pragma unroll
    for (int j = 0; j < 4; j++) {
        int row = row0 + r0 + j;
        if (row < n) {
            *(float4*)&xl[(size_t)row * HID + c0] = make_float4(
                accl[j][0] + b4l.x, accl[j][1] + b4l.y, accl[j][2] + b4l.z, accl[j][3] + b4l.w);
            *(float4*)&xr[(size_t)row * HID + c0] = make_float4(
                accr[j][0] + b4r.x, accr[j][1] + b4r.y, accr[j][2] + b4r.z, accr[j][3] + b4r.w);
        }
    }
}

// ---------------- K2: per-dst edge_weight sum + count ----------------
__global__ __launch_bounds__(256) void k_deg(const int* __restrict__ dst, const float* __restrict__ ew,
                                             float* __restrict__ wsum, float* __restrict__ wcnt, int E)
{
    int e = blockIdx.x * 256 + threadIdx.x;
    if (e < E) {
        int d = dst[e];
        atomicAdd(&wsum[d], ew[e]);
        atomicAdd(&wcnt[d], 1.0f);
    }
}

// ---------------- K3: edge pass (one wave per edge) ----------------
__global__ __launch_bounds__(256) void k_edge(const int* __restrict__ src, const int* __restrict__ dst,
                                              const float* __restrict__ ew,
                                              const float* __restrict__ xl, const float* __restrict__ xr,
                                              const float* __restrict__ We, const float* __restrict__ att,
                                              float* __restrict__ num, float* __restrict__ den, int E)
{
    __shared__ float sWe[HID], sAtt[HID];
    int t = threadIdx.x;
    if (t < HID) { sWe[t] = We[t]; sAtt[t] = att[t]; }
    __syncthreads();
    int lane = t & 63;
    int e = blockIdx.x * 4 + (t >> 6);
    if (e >= E) return;
    int s = src[e], d = dst[e];
    float w = ew[e];
    float xls = xl[(size_t)s * HID + lane];
    float xrd = xr[(size_t)d * HID + lane];
    float ef = lrelu02(xls + xrd + w * sWe[lane]);
    float p = ef * sAtt[lane];
    // reduce within 16-lane head groups
    p += __shfl_xor(p, 8);
    p += __shfl_xor(p, 4);
    p += __shfl_xor(p, 2);
    p += __shfl_xor(p, 1);
    float ex = __expf(p);   // softmax shift-invariant; |alpha| << 1, no max needed
    atomicAdd(&num[(size_t)d * HID + lane], ex * xls);
    if ((lane & 15) == 0) atomicAdd(&den[(size_t)d * HEADS + (lane >> 4)], ex);
}

// ---------------- K4a: self-loop + normalize + ELU + residual -> h ----------------
__global__ __launch_bounds__(256) void k_gat_fin(const float* __restrict__ h0,
                                                 const float* __restrict__ xl, const float* __restrict__ xr,
                                                 const float* __restrict__ wsum, const float* __restrict__ wcnt,
                                                 const float* __restrict__ num, const float* __restrict__ den,
                                                 const float* __restrict__ We, const float* __restrict__ att,
                                                 const float* __restrict__ gb,
                                                 float* __restrict__ hout, int n)
{
    __shared__ float sWe[HID], sAtt[HID], sGb[HID];
    int t = threadIdx.x;
    if (t < HID) { sWe[t] = We[t]; sAtt[t] = att[t]; sGb[t] = gb[t]; }
    __syncthreads();
    int lane = t & 63;
    int v = blockIdx.x * 4 + (t >> 6);
    if (v >= n) return;
    float la = wsum[v] / fmaxf(wcnt[v], 1.0f);
    float xlv = xl[(size_t)v * HID + lane];
    float xrv = xr[(size_t)v * HID + lane];
    float ef = lrelu02(xlv + xrv + la * sWe[lane]);
    float p = ef * sAtt[lane];
    p += __shfl_xor(p, 8);
    p += __shfl_xor(p, 4);
    p += __shfl_xor(p, 2);
    p += __shfl_xor(p, 1);
    float ex = __expf(p);
    float dtot = den[(size_t)v * HEADS + (lane >> 4)] + ex;
    float numv = num[(size_t)v * HID + lane] + ex * xlv;
    float o = numv / dtot + sGb[lane];
    float h1 = o > 0.f ? o : expm1f(o);
    hout[(size_t)v * HID + lane] = h0[(size_t)v * HID + lane] + h1;
}

// ---------------- K4b: logits = relu(h@W1+b1)@W2+b2 ----------------
__global__ __launch_bounds__(256) void k_mlp(const float* __restrict__ h,
                                             const float* __restrict__ W1, const float* __restrict__ b1,
                                             const float* __restrict__ W2, const float* __restrict__ b2,
                                             float* __restrict__ logits, int n)
{
    __shared__ float sW1[HID * HID];      // 16 KB
    __shared__ float sh[64][HID + 4];     // 17.4 KB
    __shared__ float sz[64][HID + 4];     // 17.4 KB
    __shared__ float sW2[HID * NCLS];     // 2.5 KB
    __shared__ float sb1[HID], sb2[NCLS];
    int t = threadIdx.x;
    for (int i = 4 * t; i < HID * HID; i += 1024)
        *(float4*)&sW1[i] = *(const float4*)&W1[i];
    if (4 * t < HID * NCLS)
        *(float4*)&sW2[4 * t] = *(const float4*)&W2[4 * t];
    if (t < HID)  sb1[t] = b1[t];
    if (t < NCLS) sb2[t] = b2[t];
    int row0 = blockIdx.x * 64;
    for (int i = t; i < 64 * (HID / 4); i += 256) {
        int r = i >> 4, c4 = (i & 15) * 4;
        int row = row0 + r;
        float4 v = make_float4(0.f, 0.f, 0.f, 0.f);
        if (row < n) v = *(const float4*)&h[(size_t)row * HID + c4];
        *(float4*)&sh[r][c4] = v;
    }
    __syncthreads();
    int tc = t & 15, tr = t >> 4;
    int c0 = tc * 4, r0 = tr * 4;
    float4 b14 = *(float4*)&sb1[c0];
    float acc[4][4];
    #pragma unroll
    for (int j = 0; j < 4; j++) { acc[j][0] = b14.x; acc[j][1] = b14.y; acc[j][2] = b14.z; acc[j][3] = b14.w; }
    #pragma unroll 4
    for (int k = 0; k < HID; k++) {
        float4 w = *(float4*)&sW1[k * HID + c0];
        #pragma unroll
        for (int j = 0; j < 4; j++) {
            float hv = sh[r0 + j][k];
            acc[j][0] += hv * w.x; acc[j][1] += hv * w.y;
            acc[j][2] += hv * w.z; acc[j][3] += hv * w.w;
        }
    }
    #pragma unroll
    for (int j = 0; j < 4; j++) {
        sz[r0 + j][c0 + 0] = fmaxf(acc[j][0], 0.f);
        sz[r0 + j][c0 + 1] = fmaxf(acc[j][1], 0.f);
        sz[r0 + j][c0 + 2] = fmaxf(acc[j][2], 0.f);
        sz[r0 + j][c0 + 3] = fmaxf(acc[j][3], 0.f);
    }
    __syncthreads();
    for (int i = t; i < 64 * NCLS; i += 256) {
        int r = i / NCLS, c = i - r * NCLS;
        int row = row0 + r;
        float s = sb2[c];
        #pragma unroll 8
        for (int k = 0; k < HID; k++) s += sz[r][k] * sW2[k * NCLS + c];
        if (row < n) logits[(size_t)row * NCLS + c] = s;
    }
}

extern "C" void kernel_launch(void* const* d_in, const int* in_sizes, int n_in,
                              void* d_out, int out_size, void* d_ws, size_t ws_size,
                              hipStream_t stream)
{
    const float* x   = (const float*)d_in[0];
    const float* ew  = (const float*)d_in[1];
    const float* Wp  = (const float*)d_in[2];
    const float* Wl  = (const float*)d_in[3];
    const float* bl  = (const float*)d_in[4];
    const float* Wr  = (const float*)d_in[5];
    const float* br  = (const float*)d_in[6];
    const float* att = (const float*)d_in[7];
    const float* We  = (const float*)d_in[8];
    const float* gb  = (const float*)d_in[9];
    const float* W1  = (const float*)d_in[10];
    const float* b1  = (const float*)d_in[11];
    const float* W2  = (const float*)d_in[12];
    const float* b2  = (const float*)d_in[13];
    const int*   ei  = (const int*)d_in[14];

    int n = in_sizes[0] / IN;
    int E = in_sizes[1];
    const int* src = ei;
    const int* dst = ei + E;

    float* h0   = (float*)d_ws;
    float* xl   = h0  + (size_t)n * HID;
    float* xr   = xl  + (size_t)n * HID;
    float* num  = xr  + (size_t)n * HID;     // zeroed
    float* den  = num + (size_t)n * HID;     // zeroed
    float* wsum = den + (size_t)n * HEADS;   // zeroed
    float* wcnt = wsum + n;                  // zeroed

    float* hout   = (float*)d_out;
    float* logits = hout + (size_t)n * HID;

    size_t zbytes = ((size_t)n * HID + (size_t)n * HEADS + 2 * (size_t)n) * sizeof(float);
    hipMemsetAsync(num, 0, zbytes, stream);

    int rb = (n + 63) / 64;
    k_pre <<<rb, 256, 0, stream>>>(x, Wp, h0, n);
    k_lr  <<<rb, 256, 0, stream>>>(h0, Wl, bl, Wr, br, xl, xr, n);
    k_deg <<<(E + 255) / 256, 256, 0, stream>>>(dst, ew, wsum, wcnt, E);
    k_edge<<<(E + 3) / 4, 256, 0, stream>>>(src, dst, ew, xl, xr, We, att, num, den, E);
    k_gat_fin<<<(n + 3) / 4, 256, 0, stream>>>(h0, xl, xr, wsum, wcnt, num, den, We, att, gb, hout, n);
    k_mlp <<<rb, 256, 0, stream>>>(hout, W1, b1, W2, b2, logits, n);
}

// Round 2
// 580.159 us; speedup vs baseline: 1.4514x; 1.4514x over previous
//
#include <hip/hip_runtime.h>
#include <hip/hip_bf16.h>
#include <math.h>

#define IN   128
#define HID  64
#define HEADS 4
#define NCLS 10

__device__ __forceinline__ float lrelu02(float x) { return x > 0.f ? x : 0.2f * x; }

// ---------------- K1a: h0 = x @ W_pre  (n x 128)(128 x 64) ----------------
__global__ __launch_bounds__(256) void k_pre(const float* __restrict__ x,
                                             const float* __restrict__ Wp,
                                             float* __restrict__ h0, int n)
{
    __shared__ float sW[IN * HID];        // 32 KB
    __shared__ float sx[64][IN + 4];      // 33.8 KB
    int t = threadIdx.x;
    for (int i = 4 * t; i < IN * HID; i += 1024)
        *(float4*)&sW[i] = *(const float4*)&Wp[i];
    int row0 = blockIdx.x * 64;
    for (int i = t; i < 64 * (IN / 4); i += 256) {
        int r = i >> 5;
        int c4 = (i & 31) * 4;
        int row = row0 + r;
        float4 v = make_float4(0.f, 0.f, 0.f, 0.f);
        if (row < n) v = *(const float4*)&x[(size_t)row * IN + c4];
        *(float4*)&sx[r][c4] = v;
    }
    __syncthreads();
    int tc = t & 15, tr = t >> 4;
    int c0 = tc * 4, r0 = tr * 4;
    float acc[4][4] = {};
    #pragma unroll 4
    for (int k = 0; k < IN; k++) {
        float4 w = *(float4*)&sW[k * HID + c0];
        #pragma unroll
        for (int j = 0; j < 4; j++) {
            float xv = sx[r0 + j][k];
            acc[j][0] += xv * w.x; acc[j][1] += xv * w.y;
            acc[j][2] += xv * w.z; acc[j][3] += xv * w.w;
        }
    }
    #pragma unroll
    for (int j = 0; j < 4; j++) {
        int row = row0 + r0 + j;
        if (row < n)
            *(float4*)&h0[(size_t)row * HID + c0] =
                make_float4(acc[j][0], acc[j][1], acc[j][2], acc[j][3]);
    }
}

// ---------------- K1b: xl = h0@Wl+bl, xr = h0@Wr+br ----------------
__global__ __launch_bounds__(256) void k_lr(const float* __restrict__ h0,
                                            const float* __restrict__ Wl, const float* __restrict__ bl,
                                            const float* __restrict__ Wr, const float* __restrict__ br,
                                            float* __restrict__ xl, float* __restrict__ xr, int n)
{
    __shared__ float sWl[HID * HID];
    __shared__ float sWr[HID * HID];
    __shared__ float sh[64][HID + 4];
    __shared__ float sbl[HID], sbr[HID];
    int t = threadIdx.x;
    for (int i = 4 * t; i < HID * HID; i += 1024) {
        *(float4*)&sWl[i] = *(const float4*)&Wl[i];
        *(float4*)&sWr[i] = *(const float4*)&Wr[i];
    }
    if (t < HID) { sbl[t] = bl[t]; sbr[t] = br[t]; }
    int row0 = blockIdx.x * 64;
    for (int i = t; i < 64 * (HID / 4); i += 256) {
        int r = i >> 4, c4 = (i & 15) * 4;
        int row = row0 + r;
        float4 v = make_float4(0.f, 0.f, 0.f, 0.f);
        if (row < n) v = *(const float4*)&h0[(size_t)row * HID + c4];
        *(float4*)&sh[r][c4] = v;
    }
    __syncthreads();
    int tc = t & 15, tr = t >> 4;
    int c0 = tc * 4, r0 = tr * 4;
    float accl[4][4] = {}, accr[4][4] = {};
    #pragma unroll 4
    for (int k = 0; k < HID; k++) {
        float4 wl = *(float4*)&sWl[k * HID + c0];
        float4 wr = *(float4*)&sWr[k * HID + c0];
        #pragma unroll
        for (int j = 0; j < 4; j++) {
            float hv = sh[r0 + j][k];
            accl[j][0] += hv * wl.x; accl[j][1] += hv * wl.y;
            accl[j][2] += hv * wl.z; accl[j][3] += hv * wl.w;
            accr[j][0] += hv * wr.x; accr[j][1] += hv * wr.y;
            accr[j][2] += hv * wr.z; accr[j][3] += hv * wr.w;
        }
    }
    float4 b4l = *(float4*)&sbl[c0];
    float4 b4r = *(float4*)&sbr[c0];
    #pragma unroll
    for (int j = 0; j < 4; j++) {
        int row = row0 + r0 + j;
        if (row < n) {
            *(float4*)&xl[(size_t)row * HID + c0] = make_float4(
                accl[j][0] + b4l.x, accl[j][1] + b4l.y, accl[j][2] + b4l.z, accl[j][3] + b4l.w);
            *(float4*)&xr[(size_t)row * HID + c0] = make_float4(
                accr[j][0] + b4r.x, accr[j][1] + b4r.y, accr[j][2] + b4r.z, accr[j][3] + b4r.w);
        }
    }
}

// ---------------- Sort-by-dst: histogram ----------------
__global__ __launch_bounds__(256) void k_hist(const int* __restrict__ dst, int* __restrict__ cnt, int E)
{
    int e = blockIdx.x * 256 + threadIdx.x;
    if (e < E) atomicAdd(&cnt[dst[e]], 1);
}

// ---------------- Scan stage 1: per-1024-block exclusive scan ----------------
__global__ __launch_bounds__(1024) void k_scan1(const int* __restrict__ cnt, int* __restrict__ off,
                                                int* __restrict__ bsum, int n)
{
    __shared__ int s[1024];
    int i = blockIdx.x * 1024 + threadIdx.x;
    int v = (i < n) ? cnt[i] : 0;
    s[threadIdx.x] = v;
    __syncthreads();
    for (int d = 1; d < 1024; d <<= 1) {
        int add = (threadIdx.x >= d) ? s[threadIdx.x - d] : 0;
        __syncthreads();
        s[threadIdx.x] += add;
        __syncthreads();
    }
    if (i < n) off[i] = s[threadIdx.x] - v;   // exclusive within block
    if (threadIdx.x == 1023) bsum[blockIdx.x] = s[1023];
}

// ---------------- Scan stage 2: scan of block sums (nb <= 1024) ----------------
__global__ __launch_bounds__(1024) void k_scan2(const int* __restrict__ bsum, int* __restrict__ boff, int nb)
{
    __shared__ int s[1024];
    int i = threadIdx.x;
    int v = (i < nb) ? bsum[i] : 0;
    s[i] = v;
    __syncthreads();
    for (int d = 1; d < 1024; d <<= 1) {
        int add = (i >= d) ? s[i - d] : 0;
        __syncthreads();
        s[i] += add;
        __syncthreads();
    }
    if (i < nb) boff[i] = s[i] - v;  // exclusive
}

// ---------------- Scan stage 3: add block offsets, make cursor copy ----------------
__global__ __launch_bounds__(256) void k_scan3(int* __restrict__ off, const int* __restrict__ boff,
                                               int* __restrict__ cur, int n)
{
    int i = blockIdx.x * 256 + threadIdx.x;
    if (i < n) {
        int o = off[i] + boff[i >> 10];
        off[i] = o;
        cur[i] = o;
    }
}

// ---------------- Scatter into CSR ----------------
__global__ __launch_bounds__(256) void k_scatter(const int* __restrict__ src, const int* __restrict__ dst,
                                                 const float* __restrict__ ew,
                                                 int* __restrict__ cur,
                                                 int* __restrict__ csr_s, float* __restrict__ csr_w, int E)
{
    int e = blockIdx.x * 256 + threadIdx.x;
    if (e < E) {
        int d = dst[e];
        int p = atomicAdd(&cur[d], 1);
        csr_s[p] = src[e];
        csr_w[p] = ew[e];
    }
}

// ---------------- K_agg: one wave per dst node; no atomics; fused epilogue ----------------
__global__ __launch_bounds__(256) void k_agg(const int* __restrict__ off,
                                             const int* __restrict__ csr_s, const float* __restrict__ csr_w,
                                             const float* __restrict__ xl, const float* __restrict__ xr,
                                             const float* __restrict__ h0,
                                             const float* __restrict__ We, const float* __restrict__ att,
                                             const float* __restrict__ gb,
                                             float* __restrict__ hout, int n, int E)
{
    __shared__ float sWe[HID], sAtt[HID], sGb[HID];
    int t = threadIdx.x;
    if (t < HID) { sWe[t] = We[t]; sAtt[t] = att[t]; sGb[t] = gb[t]; }
    __syncthreads();
    int lane = t & 63;
    int v = blockIdx.x * 4 + (t >> 6);
    if (v >= n) return;

    int beg = off[v];
    int end = (v == n - 1) ? E : off[v + 1];

    float we = sWe[lane], at = sAtt[lane];
    float xrv = xr[(size_t)v * HID + lane];
    float xlv = xl[(size_t)v * HID + lane];

    float num = 0.f, den = 0.f, wsum = 0.f;
    for (int i = beg; i < end; i++) {
        int s = csr_s[i];
        float w = csr_w[i];
        float xls = xl[(size_t)s * HID + lane];
        float ef = lrelu02(xls + xrv + w * we);
        float p = ef * at;
        p += __shfl_xor(p, 8);
        p += __shfl_xor(p, 4);
        p += __shfl_xor(p, 2);
        p += __shfl_xor(p, 1);
        float ex = __expf(p);   // softmax shift-invariant; |alpha| << 1, no max needed
        num += ex * xls;
        den += ex;
        wsum += w;
    }
    // analytic self-loop
    float cntf = (float)(end - beg);
    float la = wsum / fmaxf(cntf, 1.0f);
    float ef = lrelu02(xlv + xrv + la * we);
    float p = ef * at;
    p += __shfl_xor(p, 8);
    p += __shfl_xor(p, 4);
    p += __shfl_xor(p, 2);
    p += __shfl_xor(p, 1);
    float exs = __expf(p);
    den += exs;
    num += exs * xlv;

    float o = num / den + sGb[lane];
    float h1 = o > 0.f ? o : expm1f(o);
    hout[(size_t)v * HID + lane] = h0[(size_t)v * HID + lane] + h1;
}

// ---------------- K_mlp: logits = relu(h@W1+b1)@W2+b2 ----------------
__global__ __launch_bounds__(256) void k_mlp(const float* __restrict__ h,
                                             const float* __restrict__ W1, const float* __restrict__ b1,
                                             const float* __restrict__ W2, const float* __restrict__ b2,
                                             float* __restrict__ logits, int n)
{
    __shared__ float sW1[HID * HID];
    __shared__ float sh[64][HID + 4];
    __shared__ float sz[64][HID + 4];
    __shared__ float sW2[HID * NCLS];
    __shared__ float sb1[HID], sb2[NCLS];
    int t = threadIdx.x;
    for (int i = 4 * t; i < HID * HID; i += 1024)
        *(float4*)&sW1[i] = *(const float4*)&W1[i];
    if (4 * t < HID * NCLS)
        *(float4*)&sW2[4 * t] = *(const float4*)&W2[4 * t];
    if (t < HID)  sb1[t] = b1[t];
    if (t < NCLS) sb2[t] = b2[t];
    int row0 = blockIdx.x * 64;
    for (int i = t; i < 64 * (HID / 4); i += 256) {
        int r = i >> 4, c4 = (i & 15) * 4;
        int row = row0 + r;
        float4 v = make_float4(0.f, 0.f, 0.f, 0.f);
        if (row < n) v = *(const float4*)&h[(size_t)row * HID + c4];
        *(float4*)&sh[r][c4] = v;
    }
    __syncthreads();
    int tc = t & 15, tr = t >> 4;
    int c0 = tc * 4, r0 = tr * 4;
    float4 b14 = *(float4*)&sb1[c0];
    float acc[4][4];
    #pragma unroll
    for (int j = 0; j < 4; j++) { acc[j][0] = b14.x; acc[j][1] = b14.y; acc[j][2] = b14.z; acc[j][3] = b14.w; }
    #pragma unroll 4
    for (int k = 0; k < HID; k++) {
        float4 w = *(float4*)&sW1[k * HID + c0];
        #pragma unroll
        for (int j = 0; j < 4; j++) {
            float hv = sh[r0 + j][k];
            acc[j][0] += hv * w.x; acc[j][1] += hv * w.y;
            acc[j][2] += hv * w.z; acc[j][3] += hv * w.w;
        }
    }
    #pragma unroll
    for (int j = 0; j < 4; j++) {
        sz[r0 + j][c0 + 0] = fmaxf(acc[j][0], 0.f);
        sz[r0 + j][c0 + 1] = fmaxf(acc[j][1], 0.f);
        sz[r0 + j][c0 + 2] = fmaxf(acc[j][2], 0.f);
        sz[r0 + j][c0 + 3] = fmaxf(acc[j][3], 0.f);
    }
    __syncthreads();
    for (int i = t; i < 64 * NCLS; i += 256) {
        int r = i / NCLS, c = i - r * NCLS;
        int row = row0 + r;
        float s = sb2[c];
        #pragma unroll 8
        for (int k = 0; k < HID; k++) s += sz[r][k] * sW2[k * NCLS + c];
        if (row < n) logits[(size_t)row * NCLS + c] = s;
    }
}

extern "C" void kernel_launch(void* const* d_in, const int* in_sizes, int n_in,
                              void* d_out, int out_size, void* d_ws, size_t ws_size,
                              hipStream_t stream)
{
    const float* x   = (const float*)d_in[0];
    const float* ew  = (const float*)d_in[1];
    const float* Wp  = (const float*)d_in[2];
    const float* Wl  = (const float*)d_in[3];
    const float* bl  = (const float*)d_in[4];
    const float* Wr  = (const float*)d_in[5];
    const float* br  = (const float*)d_in[6];
    const float* att = (const float*)d_in[7];
    const float* We  = (const float*)d_in[8];
    const float* gb  = (const float*)d_in[9];
    const float* W1  = (const float*)d_in[10];
    const float* b1  = (const float*)d_in[11];
    const float* W2  = (const float*)d_in[12];
    const float* b2  = (const float*)d_in[13];
    const int*   ei  = (const int*)d_in[14];

    int n = in_sizes[0] / IN;
    int E = in_sizes[1];
    const int* src = ei;
    const int* dst = ei + E;

    float* h0    = (float*)d_ws;
    float* xl    = h0 + (size_t)n * HID;
    float* xr    = xl + (size_t)n * HID;
    int*   cnt   = (int*)(xr + (size_t)n * HID);   // zeroed
    int*   off   = cnt + n;
    int*   cur   = off + n;
    int*   bsum  = cur + n;
    int*   boff  = bsum + 1024;
    int*   csr_s = boff + 1024;
    float* csr_w = (float*)(csr_s + E);

    float* hout   = (float*)d_out;
    float* logits = hout + (size_t)n * HID;

    hipMemsetAsync(cnt, 0, (size_t)n * sizeof(int), stream);

    int rb = (n + 63) / 64;
    int nb = (n + 1023) / 1024;

    k_pre <<<rb, 256, 0, stream>>>(x, Wp, h0, n);
    k_lr  <<<rb, 256, 0, stream>>>(h0, Wl, bl, Wr, br, xl, xr, n);
    k_hist<<<(E + 255) / 256, 256, 0, stream>>>(dst, cnt, E);
    k_scan1<<<nb, 1024, 0, stream>>>(cnt, off, bsum, n);
    k_scan2<<<1, 1024, 0, stream>>>(bsum, boff, nb);
    k_scan3<<<(n + 255) / 256, 256, 0, stream>>>(off, boff, cur, n);
    k_scatter<<<(E + 255) / 256, 256, 0, stream>>>(src, dst, ew, cur, csr_s, csr_w, E);
    k_agg <<<(n + 3) / 4, 256, 0, stream>>>(off, csr_s, csr_w, xl, xr, h0, We, att, gb, hout, n, E);
    k_mlp <<<rb, 256, 0, stream>>>(hout, W1, b1, W2, b2, logits, n);
}

// Round 3
// 561.252 us; speedup vs baseline: 1.5003x; 1.0337x over previous
//
#include <hip/hip_runtime.h>
#include <hip/hip_bf16.h>
#include <math.h>

#define IN   128
#define HID  64
#define HEADS 4
#define NCLS 10

__device__ __forceinline__ float lrelu02(float x) { return x > 0.f ? x : 0.2f * x; }

// ---------------- K1a: h0 = x @ W_pre  (n x 128)(128 x 64) ----------------
__global__ __launch_bounds__(256) void k_pre(const float* __restrict__ x,
                                             const float* __restrict__ Wp,
                                             float* __restrict__ h0, int n)
{
    __shared__ float sW[IN * HID];        // 32 KB
    __shared__ float sx[64][IN + 4];      // 33.8 KB
    int t = threadIdx.x;
    for (int i = 4 * t; i < IN * HID; i += 1024)
        *(float4*)&sW[i] = *(const float4*)&Wp[i];
    int row0 = blockIdx.x * 64;
    for (int i = t; i < 64 * (IN / 4); i += 256) {
        int r = i >> 5;
        int c4 = (i & 31) * 4;
        int row = row0 + r;
        float4 v = make_float4(0.f, 0.f, 0.f, 0.f);
        if (row < n) v = *(const float4*)&x[(size_t)row * IN + c4];
        *(float4*)&sx[r][c4] = v;
    }
    __syncthreads();
    int tc = t & 15, tr = t >> 4;
    int c0 = tc * 4, r0 = tr * 4;
    float acc[4][4] = {};
    #pragma unroll 4
    for (int k = 0; k < IN; k++) {
        float4 w = *(float4*)&sW[k * HID + c0];
        #pragma unroll
        for (int j = 0; j < 4; j++) {
            float xv = sx[r0 + j][k];
            acc[j][0] += xv * w.x; acc[j][1] += xv * w.y;
            acc[j][2] += xv * w.z; acc[j][3] += xv * w.w;
        }
    }
    #pragma unroll
    for (int j = 0; j < 4; j++) {
        int row = row0 + r0 + j;
        if (row < n)
            *(float4*)&h0[(size_t)row * HID + c0] =
                make_float4(acc[j][0], acc[j][1], acc[j][2], acc[j][3]);
    }
}

// ---------------- K1b: xl = h0@Wl+bl, xr = h0@Wr+br ----------------
__global__ __launch_bounds__(256) void k_lr(const float* __restrict__ h0,
                                            const float* __restrict__ Wl, const float* __restrict__ bl,
                                            const float* __restrict__ Wr, const float* __restrict__ br,
                                            float* __restrict__ xl, float* __restrict__ xr, int n)
{
    __shared__ float sWl[HID * HID];
    __shared__ float sWr[HID * HID];
    __shared__ float sh[64][HID + 4];
    __shared__ float sbl[HID], sbr[HID];
    int t = threadIdx.x;
    for (int i = 4 * t; i < HID * HID; i += 1024) {
        *(float4*)&sWl[i] = *(const float4*)&Wl[i];
        *(float4*)&sWr[i] = *(const float4*)&Wr[i];
    }
    if (t < HID) { sbl[t] = bl[t]; sbr[t] = br[t]; }
    int row0 = blockIdx.x * 64;
    for (int i = t; i < 64 * (HID / 4); i += 256) {
        int r = i >> 4, c4 = (i & 15) * 4;
        int row = row0 + r;
        float4 v = make_float4(0.f, 0.f, 0.f, 0.f);
        if (row < n) v = *(const float4*)&h0[(size_t)row * HID + c4];
        *(float4*)&sh[r][c4] = v;
    }
    __syncthreads();
    int tc = t & 15, tr = t >> 4;
    int c0 = tc * 4, r0 = tr * 4;
    float accl[4][4] = {}, accr[4][4] = {};
    #pragma unroll 4
    for (int k = 0; k < HID; k++) {
        float4 wl = *(float4*)&sWl[k * HID + c0];
        float4 wr = *(float4*)&sWr[k * HID + c0];
        #pragma unroll
        for (int j = 0; j < 4; j++) {
            float hv = sh[r0 + j][k];
            accl[j][0] += hv * wl.x; accl[j][1] += hv * wl.y;
            accl[j][2] += hv * wl.z; accl[j][3] += hv * wl.w;
            accr[j][0] += hv * wr.x; accr[j][1] += hv * wr.y;
            accr[j][2] += hv * wr.z; accr[j][3] += hv * wr.w;
        }
    }
    float4 b4l = *(float4*)&sbl[c0];
    float4 b4r = *(float4*)&sbr[c0];
    #pragma unroll
    for (int j = 0; j < 4; j++) {
        int row = row0 + r0 + j;
        if (row < n) {
            *(float4*)&xl[(size_t)row * HID + c0] = make_float4(
                accl[j][0] + b4l.x, accl[j][1] + b4l.y, accl[j][2] + b4l.z, accl[j][3] + b4l.w);
            *(float4*)&xr[(size_t)row * HID + c0] = make_float4(
                accr[j][0] + b4r.x, accr[j][1] + b4r.y, accr[j][2] + b4r.z, accr[j][3] + b4r.w);
        }
    }
}

// ---------------- Sort-by-dst: histogram ----------------
__global__ __launch_bounds__(256) void k_hist(const int* __restrict__ dst, int* __restrict__ cnt, int E)
{
    int e = blockIdx.x * 256 + threadIdx.x;
    if (e < E) atomicAdd(&cnt[dst[e]], 1);
}

// ---------------- Scan stage 1 ----------------
__global__ __launch_bounds__(1024) void k_scan1(const int* __restrict__ cnt, int* __restrict__ off,
                                                int* __restrict__ bsum, int n)
{
    __shared__ int s[1024];
    int i = blockIdx.x * 1024 + threadIdx.x;
    int v = (i < n) ? cnt[i] : 0;
    s[threadIdx.x] = v;
    __syncthreads();
    for (int d = 1; d < 1024; d <<= 1) {
        int add = (threadIdx.x >= d) ? s[threadIdx.x - d] : 0;
        __syncthreads();
        s[threadIdx.x] += add;
        __syncthreads();
    }
    if (i < n) off[i] = s[threadIdx.x] - v;
    if (threadIdx.x == 1023) bsum[blockIdx.x] = s[1023];
}

// ---------------- Scan stage 2 ----------------
__global__ __launch_bounds__(1024) void k_scan2(const int* __restrict__ bsum, int* __restrict__ boff, int nb)
{
    __shared__ int s[1024];
    int i = threadIdx.x;
    int v = (i < nb) ? bsum[i] : 0;
    s[i] = v;
    __syncthreads();
    for (int d = 1; d < 1024; d <<= 1) {
        int add = (i >= d) ? s[i - d] : 0;
        __syncthreads();
        s[i] += add;
        __syncthreads();
    }
    if (i < nb) boff[i] = s[i] - v;
}

// ---------------- Scan stage 3 ----------------
__global__ __launch_bounds__(256) void k_scan3(int* __restrict__ off, const int* __restrict__ boff,
                                               int* __restrict__ cur, int n)
{
    int i = blockIdx.x * 256 + threadIdx.x;
    if (i < n) {
        int o = off[i] + boff[i >> 10];
        off[i] = o;
        cur[i] = o;
    }
}

// ---------------- Scatter into CSR (packed int2: src, weight-bits) ----------------
__global__ __launch_bounds__(256) void k_scatter(const int* __restrict__ src, const int* __restrict__ dst,
                                                 const float* __restrict__ ew,
                                                 int* __restrict__ cur,
                                                 int2* __restrict__ csr, int E)
{
    int e = blockIdx.x * 256 + threadIdx.x;
    if (e < E) {
        int d = dst[e];
        int p = atomicAdd(&cur[d], 1);
        csr[p] = make_int2(src[e], __float_as_int(ew[e]));
    }
}

// ---------------- K_agg: one wave per dst; lane-preloaded edges; 4-deep gather pipeline ----------------
__global__ __launch_bounds__(256) void k_agg(const int* __restrict__ off,
                                             const int2* __restrict__ csr,
                                             const float* __restrict__ xl, const float* __restrict__ xr,
                                             const float* __restrict__ h0,
                                             const float* __restrict__ We, const float* __restrict__ att,
                                             const float* __restrict__ gb,
                                             float* __restrict__ hout, int n, int E)
{
    __shared__ float sWe[HID], sAtt[HID], sGb[HID];
    int t = threadIdx.x;
    if (t < HID) { sWe[t] = We[t]; sAtt[t] = att[t]; sGb[t] = gb[t]; }
    __syncthreads();
    int lane = t & 63;
    int v = blockIdx.x * 4 + (t >> 6);
    if (v >= n) return;

    int beg = off[v];
    int end = (v == n - 1) ? E : off[v + 1];

    float we = sWe[lane], at = sAtt[lane];
    float xrv = xr[(size_t)v * HID + lane];
    float xlv = xl[(size_t)v * HID + lane];

    float num = 0.f, den = 0.f, wsum = 0.f;

    for (int base = beg; base < end; base += 64) {
        int m = end - base; if (m > 64) m = 64;
        // one coalesced 8B/lane load covers up to 64 edges of this node
        int sv = 0; float wv = 0.f;
        if (lane < m) {
            int2 cw = csr[base + lane];
            sv = cw.x;
            wv = __int_as_float(cw.y);
        }
        for (int j0 = 0; j0 < m; j0 += 4) {
            float xls[4], wj[4];
            // phase 1: issue up to 4 independent gathers (wave-uniform guards)
            #pragma unroll
            for (int u = 0; u < 4; u++) {
                if (j0 + u < m) {
                    int s = __shfl(sv, j0 + u);       // v_readlane (uniform idx)
                    wj[u] = __shfl(wv, j0 + u);
                    xls[u] = xl[(size_t)s * HID + lane];
                }
            }
            // phase 2: consume
            #pragma unroll
            for (int u = 0; u < 4; u++) {
                if (j0 + u < m) {
                    float ef = lrelu02(xls[u] + xrv + wj[u] * we);
                    float p = ef * at;
                    p += __shfl_xor(p, 8);
                    p += __shfl_xor(p, 4);
                    p += __shfl_xor(p, 2);
                    p += __shfl_xor(p, 1);
                    float ex = __expf(p);   // softmax shift-invariant; |alpha| << 1
                    num += ex * xls[u];
                    den += ex;
                    wsum += wj[u];
                }
            }
        }
    }

    // analytic self-loop
    float cntf = (float)(end - beg);
    float la = wsum / fmaxf(cntf, 1.0f);
    float ef = lrelu02(xlv + xrv + la * we);
    float p = ef * at;
    p += __shfl_xor(p, 8);
    p += __shfl_xor(p, 4);
    p += __shfl_xor(p, 2);
    p += __shfl_xor(p, 1);
    float exs = __expf(p);
    den += exs;
    num += exs * xlv;

    float o = num / den + sGb[lane];
    float h1 = o > 0.f ? o : expm1f(o);
    hout[(size_t)v * HID + lane] = h0[(size_t)v * HID + lane] + h1;
}

// ---------------- K_mlp: logits = relu(h@W1+b1)@W2+b2 ----------------
__global__ __launch_bounds__(256) void k_mlp(const float* __restrict__ h,
                                             const float* __restrict__ W1, const float* __restrict__ b1,
                                             const float* __restrict__ W2, const float* __restrict__ b2,
                                             float* __restrict__ logits, int n)
{
    __shared__ float sW1[HID * HID];
    __shared__ float sh[64][HID + 4];
    __shared__ float sz[64][HID + 4];
    __shared__ float sW2[HID * NCLS];
    __shared__ float sb1[HID], sb2[NCLS];
    int t = threadIdx.x;
    for (int i = 4 * t; i < HID * HID; i += 1024)
        *(float4*)&sW1[i] = *(const float4*)&W1[i];
    if (4 * t < HID * NCLS)
        *(float4*)&sW2[4 * t] = *(const float4*)&W2[4 * t];
    if (t < HID)  sb1[t] = b1[t];
    if (t < NCLS) sb2[t] = b2[t];
    int row0 = blockIdx.x * 64;
    for (int i = t; i < 64 * (HID / 4); i += 256) {
        int r = i >> 4, c4 = (i & 15) * 4;
        int row = row0 + r;
        float4 v = make_float4(0.f, 0.f, 0.f, 0.f);
        if (row < n) v = *(const float4*)&h[(size_t)row * HID + c4];
        *(float4*)&sh[r][c4] = v;
    }
    __syncthreads();
    int tc = t & 15, tr = t >> 4;
    int c0 = tc * 4, r0 = tr * 4;
    float4 b14 = *(float4*)&sb1[c0];
    float acc[4][4];
    #pragma unroll
    for (int j = 0; j < 4; j++) { acc[j][0] = b14.x; acc[j][1] = b14.y; acc[j][2] = b14.z; acc[j][3] = b14.w; }
    #pragma unroll 4
    for (int k = 0; k < HID; k++) {
        float4 w = *(float4*)&sW1[k * HID + c0];
        #pragma unroll
        for (int j = 0; j < 4; j++) {
            float hv = sh[r0 + j][k];
            acc[j][0] += hv * w.x; acc[j][1] += hv * w.y;
            acc[j][2] += hv * w.z; acc[j][3] += hv * w.w;
        }
    }
    #pragma unroll
    for (int j = 0; j < 4; j++) {
        sz[r0 + j][c0 + 0] = fmaxf(acc[j][0], 0.f);
        sz[r0 + j][c0 + 1] = fmaxf(acc[j][1], 0.f);
        sz[r0 + j][c0 + 2] = fmaxf(acc[j][2], 0.f);
        sz[r0 + j][c0 + 3] = fmaxf(acc[j][3], 0.f);
    }
    __syncthreads();
    for (int i = t; i < 64 * NCLS; i += 256) {
        int r = i / NCLS, c = i - r * NCLS;
        int row = row0 + r;
        float s = sb2[c];
        #pragma unroll 8
        for (int k = 0; k < HID; k++) s += sz[r][k] * sW2[k * NCLS + c];
        if (row < n) logits[(size_t)row * NCLS + c] = s;
    }
}

extern "C" void kernel_launch(void* const* d_in, const int* in_sizes, int n_in,
                              void* d_out, int out_size, void* d_ws, size_t ws_size,
                              hipStream_t stream)
{
    const float* x   = (const float*)d_in[0];
    const float* ew  = (const float*)d_in[1];
    const float* Wp  = (const float*)d_in[2];
    const float* Wl  = (const float*)d_in[3];
    const float* bl  = (const float*)d_in[4];
    const float* Wr  = (const float*)d_in[5];
    const float* br  = (const float*)d_in[6];
    const float* att = (const float*)d_in[7];
    const float* We  = (const float*)d_in[8];
    const float* gb  = (const float*)d_in[9];
    const float* W1  = (const float*)d_in[10];
    const float* b1  = (const float*)d_in[11];
    const float* W2  = (const float*)d_in[12];
    const float* b2  = (const float*)d_in[13];
    const int*   ei  = (const int*)d_in[14];

    int n = in_sizes[0] / IN;
    int E = in_sizes[1];
    const int* src = ei;
    const int* dst = ei + E;

    float* h0    = (float*)d_ws;
    float* xl    = h0 + (size_t)n * HID;
    float* xr    = xl + (size_t)n * HID;
    int*   cnt   = (int*)(xr + (size_t)n * HID);   // zeroed
    int*   off   = cnt + n;
    int*   cur   = off + n;
    int*   bsum  = cur + n;
    int*   boff  = bsum + 1024;
    int2*  csr   = (int2*)(boff + 1024);

    float* hout   = (float*)d_out;
    float* logits = hout + (size_t)n * HID;

    hipMemsetAsync(cnt, 0, (size_t)n * sizeof(int), stream);

    int rb = (n + 63) / 64;
    int nb = (n + 1023) / 1024;

    k_pre <<<rb, 256, 0, stream>>>(x, Wp, h0, n);
    k_lr  <<<rb, 256, 0, stream>>>(h0, Wl, bl, Wr, br, xl, xr, n);
    k_hist<<<(E + 255) / 256, 256, 0, stream>>>(dst, cnt, E);
    k_scan1<<<nb, 1024, 0, stream>>>(cnt, off, bsum, n);
    k_scan2<<<1, 1024, 0, stream>>>(bsum, boff, nb);
    k_scan3<<<(n + 255) / 256, 256, 0, stream>>>(off, boff, cur, n);
    k_scatter<<<(E + 255) / 256, 256, 0, stream>>>(src, dst, ew, cur, csr, E);
    k_agg <<<(n + 3) / 4, 256, 0, stream>>>(off, csr, xl, xr, h0, We, att, gb, hout, n, E);
    k_mlp <<<rb, 256, 0, stream>>>(hout, W1, b1, W2, b2, logits, n);
}

// Round 4
// 505.676 us; speedup vs baseline: 1.6652x; 1.1099x over previous
//
#include <hip/hip_runtime.h>
#include <hip/hip_bf16.h>
#include <math.h>

#define IN   128
#define HID  64
#define HEADS 4
#define NCLS 10

__device__ __forceinline__ float lrelu02(float x) { return fmaxf(x, 0.2f * x); }

template<int CTRL>
__device__ __forceinline__ float dppadd(float x) {
    int y = __builtin_amdgcn_update_dpp(0, __float_as_int(x), CTRL, 0xF, 0xF, true);
    return x + __int_as_float(y);
}
// sum over each 16-lane group (head): pure-VALU DPP tree
__device__ __forceinline__ float sum16(float p) {
    p = dppadd<0x128>(p);  // row_ror:8
    p = dppadd<0x124>(p);  // row_ror:4
    p = dppadd<0x4E>(p);   // quad_perm [2,3,0,1] = xor2
    p = dppadd<0xB1>(p);   // quad_perm [1,0,3,2] = xor1
    return p;
}

// ---------------- K1: h0 = x @ W_pre  (blocks < rb)  +  dst histogram (blocks >= rb) ----------------
__global__ __launch_bounds__(256) void k_pre_hist(const float* __restrict__ x,
                                                  const float* __restrict__ Wp,
                                                  float* __restrict__ h0, int n,
                                                  const int* __restrict__ dst, int* __restrict__ cnt,
                                                  int E, int rb)
{
    __shared__ float sW[IN * HID];        // 32 KB
    __shared__ float sx[64][IN + 4];      // 33.8 KB
    int t = threadIdx.x;
    if ((int)blockIdx.x >= rb) {
        int e = ((int)blockIdx.x - rb) * 256 + t;
        if (e < E) atomicAdd(&cnt[dst[e]], 1);
        return;
    }
    for (int i = 4 * t; i < IN * HID; i += 1024)
        *(float4*)&sW[i] = *(const float4*)&Wp[i];
    int row0 = blockIdx.x * 64;
    for (int i = t; i < 64 * (IN / 4); i += 256) {
        int r = i >> 5;
        int c4 = (i & 31) * 4;
        int row = row0 + r;
        float4 v = make_float4(0.f, 0.f, 0.f, 0.f);
        if (row < n) v = *(const float4*)&x[(size_t)row * IN + c4];
        *(float4*)&sx[r][c4] = v;
    }
    __syncthreads();
    int tc = t & 15, tr = t >> 4;
    int c0 = tc * 4, r0 = tr * 4;
    float acc[4][4] = {};
    #pragma unroll 4
    for (int k = 0; k < IN; k++) {
        float4 w = *(float4*)&sW[k * HID + c0];
        #pragma unroll
        for (int j = 0; j < 4; j++) {
            float xv = sx[r0 + j][k];
            acc[j][0] += xv * w.x; acc[j][1] += xv * w.y;
            acc[j][2] += xv * w.z; acc[j][3] += xv * w.w;
        }
    }
    #pragma unroll
    for (int j = 0; j < 4; j++) {
        int row = row0 + r0 + j;
        if (row < n)
            *(float4*)&h0[(size_t)row * HID + c0] =
                make_float4(acc[j][0], acc[j][1], acc[j][2], acc[j][3]);
    }
}

// ---------------- K2: xl/xr projections (blocks < rb) + scan stage1 (blocks >= rb) ----------------
__global__ __launch_bounds__(256) void k_lr_scan1(const float* __restrict__ h0,
                                                  const float* __restrict__ Wl, const float* __restrict__ bl,
                                                  const float* __restrict__ Wr, const float* __restrict__ br,
                                                  float* __restrict__ xl, float* __restrict__ xr, int n,
                                                  const int* __restrict__ cnt, int* __restrict__ off,
                                                  int* __restrict__ bsum, int rb)
{
    __shared__ float smem[12672];  // 50.7 KB, carved for both roles
    int t = threadIdx.x;

    if ((int)blockIdx.x >= rb) {
        // ---- scan1: 256 threads scan 1024 counts ----
        int* si = (int*)smem;
        int bid = (int)blockIdx.x - rb;
        int base = bid * 1024 + t * 4;
        int c0 = 0, c1 = 0, c2 = 0, c3 = 0;
        if (base + 3 < n) {
            int4 c = *(const int4*)&cnt[base];
            c0 = c.x; c1 = c.y; c2 = c.z; c3 = c.w;
        } else {
            if (base     < n) c0 = cnt[base];
            if (base + 1 < n) c1 = cnt[base + 1];
            if (base + 2 < n) c2 = cnt[base + 2];
            if (base + 3 < n) c3 = cnt[base + 3];
        }
        int lsum = c0 + c1 + c2 + c3;
        si[t] = lsum;
        __syncthreads();
        for (int d = 1; d < 256; d <<= 1) {
            int add = (t >= d) ? si[t - d] : 0;
            __syncthreads();
            si[t] += add;
            __syncthreads();
        }
        int excl = si[t] - lsum;
        if (base     < n) off[base]     = excl;
        if (base + 1 < n) off[base + 1] = excl + c0;
        if (base + 2 < n) off[base + 2] = excl + c0 + c1;
        if (base + 3 < n) off[base + 3] = excl + c0 + c1 + c2;
        if (t == 255) bsum[bid] = si[255];
        return;
    }

    float* sWl = smem;              // 4096
    float* sWr = smem + 4096;       // 4096
    float* sh  = smem + 8192;       // 64*68 = 4352
    float* sbl = smem + 12544;      // 64
    float* sbr = smem + 12608;      // 64
    for (int i = 4 * t; i < HID * HID; i += 1024) {
        *(float4*)&sWl[i] = *(const float4*)&Wl[i];
        *(float4*)&sWr[i] = *(const float4*)&Wr[i];
    }
    if (t < HID) { sbl[t] = bl[t]; sbr[t] = br[t]; }
    int row0 = blockIdx.x * 64;
    for (int i = t; i < 64 * (HID / 4); i += 256) {
        int r = i >> 4, c4 = (i & 15) * 4;
        int row = row0 + r;
        float4 v = make_float4(0.f, 0.f, 0.f, 0.f);
        if (row < n) v = *(const float4*)&h0[(size_t)row * HID + c4];
        *(float4*)&sh[r * 68 + c4] = v;
    }
    __syncthreads();
    int tc = t & 15, tr = t >> 4;
    int c0 = tc * 4, r0 = tr * 4;
    float accl[4][4] = {}, accr[4][4] = {};
    #pragma unroll 4
    for (int k = 0; k < HID; k++) {
        float4 wl = *(float4*)&sWl[k * HID + c0];
        float4 wr = *(float4*)&sWr[k * HID + c0];
        #pragma unroll
        for (int j = 0; j < 4; j++) {
            float hv = sh[(r0 + j) * 68 + k];
            accl[j][0] += hv * wl.x; accl[j][1] += hv * wl.y;
            accl[j][2] += hv * wl.z; accl[j][3] += hv * wl.w;
            accr[j][0] += hv * wr.x; accr[j][1] += hv * wr.y;
            accr[j][2] += hv * wr.z; accr[j][3] += hv * wr.w;
        }
    }
    float4 b4l = *(float4*)&sbl[c0];
    float4 b4r = *(float4*)&sbr[c0];
    #pragma unroll
    for (int j = 0; j < 4; j++) {
        int row = row0 + r0 + j;
        if (row < n) {
            *(float4*)&xl[(size_t)row * HID + c0] = make_float4(
                accl[j][0] + b4l.x, accl[j][1] + b4l.y, accl[j][2] + b4l.z, accl[j][3] + b4l.w);
            *(float4*)&xr[(size_t)row * HID + c0] = make_float4(
                accr[j][0] + b4r.x, accr[j][1] + b4r.y, accr[j][2] + b4r.z, accr[j][3] + b4r.w);
        }
    }
}

// ---------------- Scan stage 2 ----------------
__global__ __launch_bounds__(1024) void k_scan2(const int* __restrict__ bsum, int* __restrict__ boff, int nb)
{
    __shared__ int s[1024];
    int i = threadIdx.x;
    int v = (i < nb) ? bsum[i] : 0;
    s[i] = v;
    __syncthreads();
    for (int d = 1; d < 1024; d <<= 1) {
        int add = (i >= d) ? s[i - d] : 0;
        __syncthreads();
        s[i] += add;
        __syncthreads();
    }
    if (i < nb) boff[i] = s[i] - v;
}

// ---------------- Scan stage 3 ----------------
__global__ __launch_bounds__(256) void k_scan3(int* __restrict__ off, const int* __restrict__ boff,
                                               int* __restrict__ cur, int n)
{
    int i = blockIdx.x * 256 + threadIdx.x;
    if (i < n) {
        int o = off[i] + boff[i >> 10];
        off[i] = o;
        cur[i] = o;
    }
}

// ---------------- Scatter into CSR (4 edges/thread, vectorized loads) ----------------
__global__ __launch_bounds__(256) void k_scatter(const int* __restrict__ src, const int* __restrict__ dst,
                                                 const float* __restrict__ ew,
                                                 int* __restrict__ cur,
                                                 int2* __restrict__ csr, int E)
{
    int e4 = (blockIdx.x * 256 + threadIdx.x) * 4;
    if (e4 + 3 < E) {
        int4   s4 = *(const int4*)&src[e4];
        int4   d4 = *(const int4*)&dst[e4];
        float4 w4 = *(const float4*)&ew[e4];
        int p;
        p = atomicAdd(&cur[d4.x], 1); csr[p] = make_int2(s4.x, __float_as_int(w4.x));
        p = atomicAdd(&cur[d4.y], 1); csr[p] = make_int2(s4.y, __float_as_int(w4.y));
        p = atomicAdd(&cur[d4.z], 1); csr[p] = make_int2(s4.z, __float_as_int(w4.z));
        p = atomicAdd(&cur[d4.w], 1); csr[p] = make_int2(s4.w, __float_as_int(w4.w));
    } else {
        for (int e = e4; e < E; e++) {
            int p = atomicAdd(&cur[dst[e]], 1);
            csr[p] = make_int2(src[e], __float_as_int(ew[e]));
        }
    }
}

// ---------------- K_agg: one wave per dst; scalar-addressed gathers; DPP reduction ----------------
__global__ __launch_bounds__(256) void k_agg(const int* __restrict__ off,
                                             const int2* __restrict__ csr,
                                             const float* __restrict__ xl, const float* __restrict__ xr,
                                             const float* __restrict__ h0,
                                             const float* __restrict__ We, const float* __restrict__ att,
                                             const float* __restrict__ gb,
                                             float* __restrict__ hout, int n, int E)
{
    __shared__ float sWe[HID], sAtt[HID], sGb[HID];
    int t = threadIdx.x;
    if (t < HID) { sWe[t] = We[t]; sAtt[t] = att[t]; sGb[t] = gb[t]; }
    __syncthreads();
    int lane = t & 63;
    int v = blockIdx.x * 4 + (t >> 6);
    if (v >= n) return;

    int beg = off[v];
    int end = (v == n - 1) ? E : off[v + 1];

    float we = sWe[lane], at = sAtt[lane];
    float xrv = xr[(size_t)v * HID + lane];
    float xlv = xl[(size_t)v * HID + lane];

    float num = 0.f, den = 0.f, wsum = 0.f;

    for (int base = beg; base < end; base += 64) {
        int m = end - base; if (m > 64) m = 64;
        // one coalesced 8B/lane load covers up to 64 edges of this node
        int sv = 0, wvb = 0;
        if (lane < m) {
            int2 cw = csr[base + lane];
            sv = cw.x;
            wvb = cw.y;
        }
        for (int j0 = 0; j0 < m; j0 += 4) {
            float xls[4], wj[4];
            // phase 1: scalar broadcasts + up to 4 independent gathers in flight
            #pragma unroll
            for (int u = 0; u < 4; u++) {
                if (j0 + u < m) {
                    int ss = __builtin_amdgcn_readlane(sv, j0 + u);    // SGPR
                    int wb = __builtin_amdgcn_readlane(wvb, j0 + u);   // SGPR
                    wj[u] = __int_as_float(wb);
                    const float* ps = xl + ((unsigned)ss << 6);        // scalar base
                    xls[u] = ps[lane];                                 // s-base + lane voffset
                }
            }
            // phase 2: consume
            #pragma unroll
            for (int u = 0; u < 4; u++) {
                if (j0 + u < m) {
                    float ef = lrelu02(xls[u] + xrv + wj[u] * we);
                    float p = sum16(ef * at);
                    float ex = __expf(p);   // softmax shift-invariant; |alpha| << 1
                    num += ex * xls[u];
                    den += ex;
                    wsum += wj[u];
                }
            }
        }
    }

    // analytic self-loop
    float cntf = (float)(end - beg);
    float la = wsum / fmaxf(cntf, 1.0f);
    float ef = lrelu02(xlv + xrv + la * we);
    float p = sum16(ef * at);
    float exs = __expf(p);
    den += exs;
    num += exs * xlv;

    float o = num / den + sGb[lane];
    float h1 = o > 0.f ? o : expm1f(o);
    hout[(size_t)v * HID + lane] = h0[(size_t)v * HID + lane] + h1;
}

// ---------------- K_mlp: logits = relu(h@W1+b1)@W2+b2 ----------------
__global__ __launch_bounds__(256) void k_mlp(const float* __restrict__ h,
                                             const float* __restrict__ W1, const float* __restrict__ b1,
                                             const float* __restrict__ W2, const float* __restrict__ b2,
                                             float* __restrict__ logits, int n)
{
    __shared__ float sW1[HID * HID];
    __shared__ float sh[64][HID + 4];
    __shared__ float sz[64][HID + 4];
    __shared__ float sW2[HID * NCLS];
    __shared__ float sb1[HID], sb2[NCLS];
    int t = threadIdx.x;
    for (int i = 4 * t; i < HID * HID; i += 1024)
        *(float4*)&sW1[i] = *(const float4*)&W1[i];
    if (4 * t < HID * NCLS)
        *(float4*)&sW2[4 * t] = *(const float4*)&W2[4 * t];
    if (t < HID)  sb1[t] = b1[t];
    if (t < NCLS) sb2[t] = b2[t];
    int row0 = blockIdx.x * 64;
    for (int i = t; i < 64 * (HID / 4); i += 256) {
        int r = i >> 4, c4 = (i & 15) * 4;
        int row = row0 + r;
        float4 v = make_float4(0.f, 0.f, 0.f, 0.f);
        if (row < n) v = *(const float4*)&h[(size_t)row * HID + c4];
        *(float4*)&sh[r][c4] = v;
    }
    __syncthreads();
    int tc = t & 15, tr = t >> 4;
    int c0 = tc * 4, r0 = tr * 4;
    float4 b14 = *(float4*)&sb1[c0];
    float acc[4][4];
    #pragma unroll
    for (int j = 0; j < 4; j++) { acc[j][0] = b14.x; acc[j][1] = b14.y; acc[j][2] = b14.z; acc[j][3] = b14.w; }
    #pragma unroll 4
    for (int k = 0; k < HID; k++) {
        float4 w = *(float4*)&sW1[k * HID + c0];
        #pragma unroll
        for (int j = 0; j < 4; j++) {
            float hv = sh[r0 + j][k];
            acc[j][0] += hv * w.x; acc[j][1] += hv * w.y;
            acc[j][2] += hv * w.z; acc[j][3] += hv * w.w;
        }
    }
    #pragma unroll
    for (int j = 0; j < 4; j++) {
        sz[r0 + j][c0 + 0] = fmaxf(acc[j][0], 0.f);
        sz[r0 + j][c0 + 1] = fmaxf(acc[j][1], 0.f);
        sz[r0 + j][c0 + 2] = fmaxf(acc[j][2], 0.f);
        sz[r0 + j][c0 + 3] = fmaxf(acc[j][3], 0.f);
    }
    __syncthreads();
    for (int i = t; i < 64 * NCLS; i += 256) {
        int r = i / NCLS, c = i - r * NCLS;
        int row = row0 + r;
        float s = sb2[c];
        #pragma unroll 8
        for (int k = 0; k < HID; k++) s += sz[r][k] * sW2[k * NCLS + c];
        if (row < n) logits[(size_t)row * NCLS + c] = s;
    }
}

extern "C" void kernel_launch(void* const* d_in, const int* in_sizes, int n_in,
                              void* d_out, int out_size, void* d_ws, size_t ws_size,
                              hipStream_t stream)
{
    const float* x   = (const float*)d_in[0];
    const float* ew  = (const float*)d_in[1];
    const float* Wp  = (const float*)d_in[2];
    const float* Wl  = (const float*)d_in[3];
    const float* bl  = (const float*)d_in[4];
    const float* Wr  = (const float*)d_in[5];
    const float* br  = (const float*)d_in[6];
    const float* att = (const float*)d_in[7];
    const float* We  = (const float*)d_in[8];
    const float* gb  = (const float*)d_in[9];
    const float* W1  = (const float*)d_in[10];
    const float* b1  = (const float*)d_in[11];
    const float* W2  = (const float*)d_in[12];
    const float* b2  = (const float*)d_in[13];
    const int*   ei  = (const int*)d_in[14];

    int n = in_sizes[0] / IN;
    int E = in_sizes[1];
    const int* src = ei;
    const int* dst = ei + E;

    float* h0    = (float*)d_ws;
    float* xl    = h0 + (size_t)n * HID;
    float* xr    = xl + (size_t)n * HID;
    int*   cnt   = (int*)(xr + (size_t)n * HID);   // zeroed
    int*   off   = cnt + n;
    int*   cur   = off + n;
    int*   bsum  = cur + n;
    int*   boff  = bsum + 1024;
    int2*  csr   = (int2*)(boff + 1024);

    float* hout   = (float*)d_out;
    float* logits = hout + (size_t)n * HID;

    hipMemsetAsync(cnt, 0, (size_t)n * sizeof(int), stream);

    int rb = (n + 63) / 64;
    int nb = (n + 1023) / 1024;
    int Eb = (E + 255) / 256;

    k_pre_hist<<<rb + Eb, 256, 0, stream>>>(x, Wp, h0, n, dst, cnt, E, rb);
    k_lr_scan1<<<rb + nb, 256, 0, stream>>>(h0, Wl, bl, Wr, br, xl, xr, n, cnt, off, bsum, rb);
    k_scan2<<<1, 1024, 0, stream>>>(bsum, boff, nb);
    k_scan3<<<(n + 255) / 256, 256, 0, stream>>>(off, boff, cur, n);
    k_scatter<<<(E / 4 + 255) / 256, 256, 0, stream>>>(src, dst, ew, cur, csr, E);
    k_agg <<<(n + 3) / 4, 256, 0, stream>>>(off, csr, xl, xr, h0, We, att, gb, hout, n, E);
    k_mlp <<<rb, 256, 0, stream>>>(hout, W1, b1, W2, b2, logits, n);
}